// Round 5
// baseline (111.511 us; speedup 1.0000x reference)
//
#include <hip/hip_runtime.h>
#include <math.h>

#define LENL 96
#define NCH 32
#define CCH 16
#define NEXP 4
#define NB 512
#define SPLIT 8
#define TWO_PI_D 6.283185307179586476925286766559
#define TAU_MARGIN 1e-4f

// ---------------- Kernel 0: exact twiddle tables (runs once per call) ----------------
__global__ __launch_bounds__(128) void k0_init(double2* __restrict__ tw64,
                                               float2* __restrict__ tw32)
{
    int t = threadIdx.x;
    if (t < LENL) {
        double ang = TWO_PI_D * (double)t / 96.0;
        double c = cos(ang), s = sin(ang);
        tw64[t] = make_double2(c, s);
        tw32[t] = make_float2((float)c, (float)s);
    }
}

// ---------------- Kernel 1: gather + fp32 DFT + top-4/margin + flags ----------------
// grid = NB*4 blocks of 128. Block (b,q): series n0=8q..8q+7. Wave w: 4 series,
// lane = freq-1 (47 active). Twiddles: per-lane rotation, refreshed every 8 steps
// from the exact table (error ~1e-6 rel).
__global__ __launch_bounds__(128) void k1_main(
    const float* __restrict__ x,        // (512,96,32,16)
    const float* __restrict__ W_start,  // (1,32)
    const float2* __restrict__ tw32g,   // (96) exact (cos,sin)
    float* __restrict__ yPart,          // (2048,96)
    float2* __restrict__ selAB,         // (16384*3)
    int* __restrict__ selFq,            // (16384*3)
    unsigned char* __restrict__ flags)  // (16384)
{
    const int blk = blockIdx.x;
    const int b = blk >> 2, q = blk & 3;
    const int n0 = q << 3;
    const int t = threadIdx.x;
    const int w = t >> 6, lane = t & 63;

    __shared__ __align__(16) float xs[8][100];   // stride 100: bank 4n+l, conflict-free
    __shared__ float2 twl[LENL];
    __shared__ float mags[8][48], reF[8][48], imF[8][48];

    if (t < LENL) twl[t] = tw32g[t];
    for (int idx = t; idx < 8 * LENL; idx += 128) {
        int l = idx >> 3, n = idx & 7;
        xs[n][l] = x[(((size_t)b * LENL + l) * NCH + (n0 + n)) * CCH];
    }
    __syncthreads();

    if (lane < 47) {
        const int f = lane + 1;
        const float2 stp = twl[f];
        const float stpx = stp.x, stpy = stp.y;
        int f8 = (f << 3) % LENL;
        float ar0 = 0, ai0 = 0, ar1 = 0, ai1 = 0;
        float ar2 = 0, ai2 = 0, ar3 = 0, ai3 = 0;
        const float4* p0 = (const float4*)&xs[w * 4 + 0][0];
        const float4* p1 = (const float4*)&xs[w * 4 + 1][0];
        const float4* p2 = (const float4*)&xs[w * 4 + 2][0];
        const float4* p3 = (const float4*)&xs[w * 4 + 3][0];
        int m = 0;
        for (int g = 0; g < 12; ++g) {          // 8 samples per group
            float2 tf = twl[m];                 // exact refresh at l = 8g
            float c = tf.x, s = tf.y;
            float4 A0 = p0[2 * g], B0 = p0[2 * g + 1];
            float4 A1 = p1[2 * g], B1 = p1[2 * g + 1];
            float4 A2 = p2[2 * g], B2 = p2[2 * g + 1];
            float4 A3 = p3[2 * g], B3 = p3[2 * g + 1];
            #define STEP(v0, v1, v2, v3) { \
                ar0 = fmaf(c, (v0), ar0); ai0 = fmaf(s, (v0), ai0); \
                ar1 = fmaf(c, (v1), ar1); ai1 = fmaf(s, (v1), ai1); \
                ar2 = fmaf(c, (v2), ar2); ai2 = fmaf(s, (v2), ai2); \
                ar3 = fmaf(c, (v3), ar3); ai3 = fmaf(s, (v3), ai3); \
                float cn = fmaf(c, stpx, -(s * stpy)); \
                float sn = fmaf(c, stpy, s * stpx); \
                c = cn; s = sn; }
            STEP(A0.x, A1.x, A2.x, A3.x)
            STEP(A0.y, A1.y, A2.y, A3.y)
            STEP(A0.z, A1.z, A2.z, A3.z)
            STEP(A0.w, A1.w, A2.w, A3.w)
            STEP(B0.x, B1.x, B2.x, B3.x)
            STEP(B0.y, B1.y, B2.y, B3.y)
            STEP(B0.z, B1.z, B2.z, B3.z)
            STEP(B0.w, B1.w, B2.w, B3.w)
            #undef STEP
            m += f8; if (m >= LENL) m -= LENL;
        }
        // Xr = ar, Xi = -ai  (rfft convention, matches prior passing rounds)
        mags[w * 4 + 0][lane] = fmaf(ar0, ar0, ai0 * ai0); reF[w * 4 + 0][lane] = ar0; imF[w * 4 + 0][lane] = -ai0;
        mags[w * 4 + 1][lane] = fmaf(ar1, ar1, ai1 * ai1); reF[w * 4 + 1][lane] = ar1; imF[w * 4 + 1][lane] = -ai1;
        mags[w * 4 + 2][lane] = fmaf(ar2, ar2, ai2 * ai2); reF[w * 4 + 2][lane] = ar2; imF[w * 4 + 2][lane] = -ai2;
        mags[w * 4 + 3][lane] = fmaf(ar3, ar3, ai3 * ai3); reF[w * 4 + 3][lane] = ar3; imF[w * 4 + 3][lane] = -ai3;
    }
    __syncthreads();

    if (t < 8) {
        float m1 = -1.f, m2 = -1.f, m3 = -1.f, m4 = -1.f;
        int i1 = 0, i2 = 0, i3 = 0;
        for (int fi = 0; fi < 47; ++fi) {
            float mg = mags[t][fi];
            if (mg > m1)      { m4 = m3; m3 = m2; i3 = i2; m2 = m1; i2 = i1; m1 = mg; i1 = fi; }
            else if (mg > m2) { m4 = m3; m3 = m2; i3 = i2; m2 = mg; i2 = fi; }
            else if (mg > m3) { m4 = m3; m3 = mg; i3 = fi; }
            else if (mg > m4) { m4 = mg; }
        }
        const int n = n0 + t;
        const int sgl = b * NCH + n;
        flags[sgl] = ((m3 - m4) <= TAU_MARGIN * m1) ? 1 : 0;
        const float sc = W_start[n] * (2.0f / 96.0f);
        const size_t base = (size_t)sgl * 3;
        selFq[base + 0] = i1 + 1; selAB[base + 0] = make_float2(sc * reF[t][i1], sc * imF[t][i1]);
        selFq[base + 1] = i2 + 1; selAB[base + 1] = make_float2(sc * reF[t][i2], sc * imF[t][i2]);
        selFq[base + 2] = i3 + 1; selAB[base + 2] = make_float2(sc * reF[t][i3], sc * imF[t][i3]);
    }

    if (t < LENL) {
        float yv = 0.f;
        #pragma unroll
        for (int n = 0; n < 8; ++n)
            yv += xs[n][t] * W_start[n0 + n];
        yPart[(size_t)blk * LENL + t] = yv;
    }
}

// ---------------- Kernel 1b: fp64 redo of margin-flagged series (rare) ----------------
// grid = NB blocks of 64 (1 wave). Block b scans its 32 series' flags.
__global__ __launch_bounds__(64) void k1b_fix(
    const float* __restrict__ x,
    const float* __restrict__ W_start,
    const double2* __restrict__ tw64,
    const unsigned char* __restrict__ flags,
    float2* __restrict__ selAB,
    int* __restrict__ selFq)
{
    const int b = blockIdx.x;
    const int lane = threadIdx.x;
    int fl = (lane < NCH) ? (int)flags[b * NCH + lane] : 0;
    unsigned long long mask = __ballot(fl != 0);
    if (mask == 0ull) return;

    __shared__ double smag[48];
    __shared__ float sre[48], sim[48];

    while (mask) {
        int n = __ffsll(mask) - 1;
        mask &= mask - 1;
        if (lane < 47) {
            const int f = lane + 1;
            double ar = 0.0, ai = 0.0;
            int m = 0;
            #pragma unroll 4
            for (int l = 0; l < LENL; ++l) {
                double v = (double)x[(((size_t)b * LENL + l) * NCH + n) * CCH];
                double2 tw = tw64[m];
                ar = fma(tw.x, v, ar);
                ai = fma(tw.y, v, ai);
                m += f; if (m >= LENL) m -= LENL;
            }
            smag[lane] = ar * ar + ai * ai;
            sre[lane] = (float)ar;
            sim[lane] = (float)(-ai);
        }
        __syncthreads();
        if (lane == 0) {
            double m1 = -1.0, m2 = -1.0, m3 = -1.0;
            int i1 = 0, i2 = 0, i3 = 0;
            for (int fi = 0; fi < 47; ++fi) {
                double mg = smag[fi];
                if (mg > m1)      { m3 = m2; i3 = i2; m2 = m1; i2 = i1; m1 = mg; i1 = fi; }
                else if (mg > m2) { m3 = m2; i3 = i2; m2 = mg; i2 = fi; }
                else if (mg > m3) { m3 = mg; i3 = fi; }
            }
            const float sc = W_start[n] * (2.0f / 96.0f);
            const size_t base = ((size_t)b * NCH + n) * 3;
            selFq[base + 0] = i1 + 1; selAB[base + 0] = make_float2(sc * sre[i1], sc * sim[i1]);
            selFq[base + 1] = i2 + 1; selAB[base + 1] = make_float2(sc * sre[i2], sc * sim[i2]);
            selFq[base + 2] = i3 + 1; selAB[base + 2] = make_float2(sc * sre[i3], sc * sim[i3]);
        }
        __syncthreads();
    }
}

// ---------------- Kernel 2: trend + seasonal + logits + gates + M (per b) ----------------
__global__ __launch_bounds__(128) void k2_gate(
    const float* __restrict__ yPart,
    const float2* __restrict__ selAB,
    const int* __restrict__ selFq,
    const float2* __restrict__ tw32g,
    const float* __restrict__ b_start,
    const float* __restrict__ W_gate,   // (4,96)
    const float* __restrict__ b_gate,   // (4,)
    const float* __restrict__ W_exp,    // (4,16,16)
    const float* __restrict__ b_exp,    // (4,16)
    float* __restrict__ Mws, float* __restrict__ biasws, float* __restrict__ gws)
{
    const int b = blockIdx.x, t = threadIdx.x;
    __shared__ float2 twf[LENL];        // (cos, -sin)
    __shared__ float As[96], Bs[96];
    __shared__ int Fs[96];
    __shared__ float g_sh[LENL];
    __shared__ float logit_s[NEXP];
    __shared__ float gsel[2];
    __shared__ int esel[2];

    if (t < LENL) {
        float2 tg = tw32g[t];
        twf[t] = make_float2(tg.x, -tg.y);
        float2 ab = selAB[(size_t)b * 96 + t];
        As[t] = ab.x; Bs[t] = ab.y;
        Fs[t] = selFq[(size_t)b * 96 + t];
        g_sh[t] = yPart[((size_t)b * 4 + 0) * LENL + t]
                + yPart[((size_t)b * 4 + 1) * LENL + t]
                + yPart[((size_t)b * 4 + 2) * LENL + t]
                + yPart[((size_t)b * 4 + 3) * LENL + t];
    }
    __syncthreads();

    float gval = 0.f;
    if (t < LENL) {
        float s4 = 0.f;
        #pragma unroll
        for (int j = -1; j <= 2; ++j) {
            int li = t + j; li = li < 0 ? 0 : (li > 95 ? 95 : li);
            s4 += g_sh[li];
        }
        float s8 = s4;
        {
            int li;
            li = t - 3; li = li < 0 ? 0 : li; s8 += g_sh[li];
            li = t - 2; li = li < 0 ? 0 : li; s8 += g_sh[li];
            li = t + 3; li = li > 95 ? 95 : li; s8 += g_sh[li];
            li = t + 4; li = li > 95 ? 95 : li; s8 += g_sh[li];
        }
        float s12 = s8;
        {
            int li;
            li = t - 5; li = li < 0 ? 0 : li; s12 += g_sh[li];
            li = t - 4; li = li < 0 ? 0 : li; s12 += g_sh[li];
            li = t + 5; li = li > 95 ? 95 : li; s12 += g_sh[li];
            li = t + 6; li = li > 95 ? 95 : li; s12 += g_sh[li];
        }
        float tr = (s4 * 0.25f + s8 * 0.125f + s12 * (1.f / 12.f)) * (1.f / 3.f);
        float se = 0.f;
        for (int k = 0; k < 96; ++k) {
            int m = (Fs[k] * t) % LENL;
            float2 c = twf[m];
            se += As[k] * c.x + Bs[k] * c.y;
        }
        gval = g_sh[t] + tr + se + b_start[0];
    }
    __syncthreads();
    if (t < LENL) g_sh[t] = gval;
    __syncthreads();

    if (t < NEXP) {
        float acc = b_gate[t];
        for (int l = 0; l < LENL; ++l) acc += g_sh[l] * W_gate[t * LENL + l];
        logit_s[t] = acc;
    }
    __syncthreads();

    if (t == 0) {
        int i1 = 0;
        for (int e = 1; e < NEXP; ++e) if (logit_s[e] > logit_s[i1]) i1 = e;
        int i2 = (i1 == 0) ? 1 : 0;
        for (int e = 0; e < NEXP; ++e) if (e != i1 && logit_s[e] > logit_s[i2]) i2 = e;
        float v1 = logit_s[i1], v2 = logit_s[i2];
        float e2v = expf(v2 - v1);
        float inv = 1.f / (1.f + e2v);
        esel[0] = i1; esel[1] = i2; gsel[0] = inv; gsel[1] = e2v * inv;
        for (int e = 0; e < NEXP; ++e)
            gws[b * NEXP + e] = (e == i1) ? inv : ((e == i2) ? e2v * inv : 0.f);
    }
    __syncthreads();

    {
        float ga = gsel[0], gb = gsel[1];
        int ea = esel[0], eb = esel[1];
        for (int idx = t; idx < CCH * CCH; idx += 128)
            Mws[b * 256 + idx] = ga * W_exp[ea * 256 + idx] + gb * W_exp[eb * 256 + idx];
        if (t < CCH)
            biasws[b * CCH + t] = ga * b_exp[ea * CCH + t] + gb * b_exp[eb * CCH + t];
    }
}

// ---------------- Kernel 3: out = x + x @ M_b + bias_b ----------------
__global__ __launch_bounds__(256) void k2_out(
    const float* __restrict__ x,
    const float* __restrict__ Mws,
    const float* __restrict__ biasws,
    float* __restrict__ out)
{
    const int blk = blockIdx.x;
    const int b = blk >> 3;
    const int chunk = blk & 7;
    const int t = threadIdx.x;
    const int lane = t & 63;
    const int wv = t >> 6;
    const int cg = lane & 3;
    const int prow = (wv << 4) + (lane >> 2);

    const float* Mb = Mws + b * 256 + cg * 4;
    float4 m0  = *(const float4*)(Mb + 0 * 16);
    float4 m1  = *(const float4*)(Mb + 1 * 16);
    float4 m2  = *(const float4*)(Mb + 2 * 16);
    float4 m3  = *(const float4*)(Mb + 3 * 16);
    float4 m4  = *(const float4*)(Mb + 4 * 16);
    float4 m5  = *(const float4*)(Mb + 5 * 16);
    float4 m6  = *(const float4*)(Mb + 6 * 16);
    float4 m7  = *(const float4*)(Mb + 7 * 16);
    float4 m8  = *(const float4*)(Mb + 8 * 16);
    float4 m9  = *(const float4*)(Mb + 9 * 16);
    float4 m10 = *(const float4*)(Mb + 10 * 16);
    float4 m11 = *(const float4*)(Mb + 11 * 16);
    float4 m12 = *(const float4*)(Mb + 12 * 16);
    float4 m13 = *(const float4*)(Mb + 13 * 16);
    float4 m14 = *(const float4*)(Mb + 14 * 16);
    float4 m15 = *(const float4*)(Mb + 15 * 16);
    float4 bias = *(const float4*)(biasws + b * CCH + cg * 4);

    const size_t base = (size_t)b * (LENL * NCH * CCH);
    const float* xb = x + base;
    float* ob = out + base;
    const int posBase = chunk * (LENL * NCH / SPLIT);

    #pragma unroll
    for (int i = 0; i < (LENL * NCH / SPLIT) / 64; ++i) {
        int pos = posBase + i * 64 + prow;
        const float* xr = xb + (size_t)pos * CCH;
        float4 x0 = *(const float4*)(xr + 0);
        float4 x1 = *(const float4*)(xr + 4);
        float4 x2 = *(const float4*)(xr + 8);
        float4 x3 = *(const float4*)(xr + 12);
        float4 acc = bias;
        #define STEPF(v, M) acc.x += (v) * (M).x; acc.y += (v) * (M).y; acc.z += (v) * (M).z; acc.w += (v) * (M).w;
        STEPF(x0.x, m0)  STEPF(x0.y, m1)  STEPF(x0.z, m2)  STEPF(x0.w, m3)
        STEPF(x1.x, m4)  STEPF(x1.y, m5)  STEPF(x1.z, m6)  STEPF(x1.w, m7)
        STEPF(x2.x, m8)  STEPF(x2.y, m9)  STEPF(x2.z, m10) STEPF(x2.w, m11)
        STEPF(x3.x, m12) STEPF(x3.y, m13) STEPF(x3.z, m14) STEPF(x3.w, m15)
        #undef STEPF
        float4 xo = (cg == 0) ? x0 : ((cg == 1) ? x1 : ((cg == 2) ? x2 : x3));
        acc.x += xo.x; acc.y += xo.y; acc.z += xo.z; acc.w += xo.w;
        *(float4*)(ob + (size_t)pos * CCH + cg * 4) = acc;
    }
}

// ---------------- Kernel 4: balance loss ----------------
__global__ __launch_bounds__(256) void k3_loss(
    const float* __restrict__ gws, float* __restrict__ loss_out)
{
    __shared__ float sh[8][256];
    const int t = threadIdx.x;
    float imp[4] = {0, 0, 0, 0}, ld[4] = {0, 0, 0, 0};
    for (int b = t; b < NB; b += 256) {
        #pragma unroll
        for (int e = 0; e < 4; ++e) {
            float v = gws[b * 4 + e];
            imp[e] += v;
            ld[e] += (v > 0.f) ? 1.f : 0.f;
        }
    }
    #pragma unroll
    for (int e = 0; e < 4; ++e) { sh[e][t] = imp[e]; sh[4 + e][t] = ld[e]; }
    __syncthreads();
    if (t < 8) {
        float s = 0.f;
        for (int i = 0; i < 256; ++i) s += sh[t][i];
        sh[t][0] = s;
    }
    __syncthreads();
    if (t == 0) {
        float a = sh[0][0], b2 = sh[1][0], c = sh[2][0], d = sh[3][0];
        float mean = (a + b2 + c + d) * 0.25f;
        float var = ((a - mean) * (a - mean) + (b2 - mean) * (b2 - mean) +
                     (c - mean) * (c - mean) + (d - mean) * (d - mean)) * (1.f / 3.f);
        float L1 = var / (mean * mean + 1e-10f);
        a = sh[4][0]; b2 = sh[5][0]; c = sh[6][0]; d = sh[7][0];
        mean = (a + b2 + c + d) * 0.25f;
        var = ((a - mean) * (a - mean) + (b2 - mean) * (b2 - mean) +
               (c - mean) * (c - mean) + (d - mean) * (d - mean)) * (1.f / 3.f);
        float L2 = var / (mean * mean + 1e-10f);
        *loss_out = 0.01f * (L1 + L2);
    }
}

extern "C" void kernel_launch(void* const* d_in, const int* in_sizes, int n_in,
                              void* d_out, int out_size, void* d_ws, size_t ws_size,
                              hipStream_t stream)
{
    const float* x       = (const float*)d_in[0];
    const float* W_start = (const float*)d_in[1];
    const float* b_start = (const float*)d_in[2];
    const float* W_gate  = (const float*)d_in[3];
    const float* b_gate  = (const float*)d_in[4];
    const float* W_exp   = (const float*)d_in[5];
    const float* b_exp   = (const float*)d_in[6];
    float* out = (float*)d_out;

    float* ws = (float*)d_ws;
    double2* tw64       = (double2*)ws;                       // 96*4 floats
    float2* tw32        = (float2*)(ws + 384);                // 96*2 floats
    float* yPart        = ws + 576;                           // 2048*96 = 196608
    float2* selAB       = (float2*)(ws + 576 + 196608);       // 49152*2 floats
    int* selFq          = (int*)(ws + 576 + 196608 + 98304);  // 49152
    unsigned char* flags = (unsigned char*)(ws + 576 + 196608 + 98304 + 49152); // 16384 B = 4096 floats
    float* Mws          = ws + 576 + 196608 + 98304 + 49152 + 4096;  // 131072
    float* biasws       = Mws + NB * 256;                     // 8192
    float* gws          = biasws + NB * CCH;                  // 2048

    k0_init<<<1, 128, 0, stream>>>(tw64, tw32);
    k1_main<<<NB * 4, 128, 0, stream>>>(x, W_start, tw32, yPart, selAB, selFq, flags);
    k1b_fix<<<NB, 64, 0, stream>>>(x, W_start, tw64, flags, selAB, selFq);
    k2_gate<<<NB, 128, 0, stream>>>(yPart, selAB, selFq, tw32, b_start,
                                    W_gate, b_gate, W_exp, b_exp, Mws, biasws, gws);
    k2_out<<<NB * SPLIT, 256, 0, stream>>>(x, Mws, biasws, out);
    k3_loss<<<1, 256, 0, stream>>>(gws, out + (size_t)out_size - 1);
}

// Round 6
// 80.328 us; speedup vs baseline: 1.3882x; 1.3882x over previous
//
#include <hip/hip_runtime.h>
#include <math.h>

#define LENL 96
#define NCH 32
#define CCH 16
#define NEXP 4
#define NB 512
#define SPLIT 8
#define TWO_PI_D 6.283185307179586476925286766559

// ---------------- Kernel 0: exact fp64 twiddle table ----------------
__global__ __launch_bounds__(128) void k0_init(double2* __restrict__ tw64)
{
    int t = threadIdx.x;
    if (t < LENL) {
        double ang = TWO_PI_D * (double)t / 96.0;
        tw64[t] = make_double2(cos(ang), sin(ang));
    }
}

// ---------------- Kernel A: full gating path, one block per batch row ----------------
// Phase 1: COALESCED read of x[b] (all 16 channels, 192 KB), extract c=0 -> LDS fp64.
// Phase 2: fp64 Goertzel DFT (wave w = series 8w..8w+7, lane = freq-1, 47 active).
// Phase 3: top-3 |X|^2 per series (fp64, strict >). Phase 4: y = x.Ws.
// Phase 5: trend(y) + seasonal. Phase 6: logits/top-2/softmax -> M_b, bias_b, gates.
__global__ __launch_bounds__(256) void kA_gate(
    const float* __restrict__ x,        // (512,96,32,16)
    const double2* __restrict__ tw64g,  // (96) exact (cos,sin)
    const float* __restrict__ W_start,  // (1,32)
    const float* __restrict__ b_start,  // (1,)
    const float* __restrict__ W_gate,   // (4,96)
    const float* __restrict__ b_gate,   // (4,)
    const float* __restrict__ W_exp,    // (4,16,16)
    const float* __restrict__ b_exp,    // (4,16)
    float* __restrict__ Mws,            // (512,256)
    float* __restrict__ biasws,         // (512,16)
    float* __restrict__ gws)            // (512,4)
{
    const int b = blockIdx.x, t = threadIdx.x;
    const int w = t >> 6, lane = t & 63;

    __shared__ __align__(16) double xd[NCH][98];   // row = series n, 96 samples + pad
    __shared__ double mags[NCH][49];
    __shared__ float reF[NCH][49], imF[NCH][49];
    __shared__ __align__(16) double2 tw64s[LENL];
    __shared__ float2 twf[LENL];                   // (cos, -sin) fp32
    __shared__ float Wsm[NCH];
    __shared__ float As[96], Bs[96];
    __shared__ int Fs[96];
    __shared__ float g_sh[LENL];
    __shared__ float logit_s[NEXP];
    __shared__ float gsel[2];
    __shared__ int esel[2];

    if (t < LENL) {
        double2 tg = tw64g[t];
        tw64s[t] = tg;
        twf[t] = make_float2((float)tg.x, (float)(-tg.y));
    }
    if (t < NCH) Wsm[t] = W_start[t];

    // ---- Phase 1: coalesced full-width read; keep only channel 0.
    // 3072 rows x 64 B = 12288 float4, 48 per thread. The keep-alive asm forces
    // the full float4 load for every lane (prevents shrinking to a strided load).
    {
        const float4* xb4 = (const float4*)(x + (size_t)b * (LENL * NCH * CCH));
        #pragma unroll
        for (int i = 0; i < 48; ++i) {
            int idx = t + (i << 8);
            float4 v = xb4[idx];
            asm volatile("" :: "v"(v.x), "v"(v.y), "v"(v.z), "v"(v.w));
            if ((idx & 3) == 0) {
                int pos = idx >> 2;                 // pos = l*32 + n
                xd[pos & 31][pos >> 5] = (double)v.x;
            }
        }
    }
    __syncthreads();

    // ---- Phase 2: fp64 Goertzel, 8 series per lane-freq
    if (lane < 47) {
        const double2 twv = tw64s[lane + 1];
        const double c2 = 2.0 * twv.x;
        const int s0 = w << 3;
        double s1_0=0,s2_0=0,s1_1=0,s2_1=0,s1_2=0,s2_2=0,s1_3=0,s2_3=0;
        double s1_4=0,s2_4=0,s1_5=0,s2_5=0,s1_6=0,s2_6=0,s1_7=0,s2_7=0;
        const double2* p0 = (const double2*)&xd[s0 + 0][0];
        const double2* p1 = (const double2*)&xd[s0 + 1][0];
        const double2* p2 = (const double2*)&xd[s0 + 2][0];
        const double2* p3 = (const double2*)&xd[s0 + 3][0];
        const double2* p4 = (const double2*)&xd[s0 + 4][0];
        const double2* p5 = (const double2*)&xd[s0 + 5][0];
        const double2* p6 = (const double2*)&xd[s0 + 6][0];
        const double2* p7 = (const double2*)&xd[s0 + 7][0];
        #pragma unroll 2
        for (int j = 0; j < 48; ++j) {
            double2 v0 = p0[j], v1 = p1[j], v2 = p2[j], v3 = p3[j];
            double2 v4 = p4[j], v5 = p5[j], v6 = p6[j], v7 = p7[j];
            double tt;
            tt = fma(c2, s1_0, v0.x - s2_0); s2_0 = s1_0; s1_0 = tt;
            tt = fma(c2, s1_1, v1.x - s2_1); s2_1 = s1_1; s1_1 = tt;
            tt = fma(c2, s1_2, v2.x - s2_2); s2_2 = s1_2; s1_2 = tt;
            tt = fma(c2, s1_3, v3.x - s2_3); s2_3 = s1_3; s1_3 = tt;
            tt = fma(c2, s1_4, v4.x - s2_4); s2_4 = s1_4; s1_4 = tt;
            tt = fma(c2, s1_5, v5.x - s2_5); s2_5 = s1_5; s1_5 = tt;
            tt = fma(c2, s1_6, v6.x - s2_6); s2_6 = s1_6; s1_6 = tt;
            tt = fma(c2, s1_7, v7.x - s2_7); s2_7 = s1_7; s1_7 = tt;
            tt = fma(c2, s1_0, v0.y - s2_0); s2_0 = s1_0; s1_0 = tt;
            tt = fma(c2, s1_1, v1.y - s2_1); s2_1 = s1_1; s1_1 = tt;
            tt = fma(c2, s1_2, v2.y - s2_2); s2_2 = s1_2; s1_2 = tt;
            tt = fma(c2, s1_3, v3.y - s2_3); s2_3 = s1_3; s1_3 = tt;
            tt = fma(c2, s1_4, v4.y - s2_4); s2_4 = s1_4; s1_4 = tt;
            tt = fma(c2, s1_5, v5.y - s2_5); s2_5 = s1_5; s1_5 = tt;
            tt = fma(c2, s1_6, v6.y - s2_6); s2_6 = s1_6; s1_6 = tt;
            tt = fma(c2, s1_7, v7.y - s2_7); s2_7 = s1_7; s1_7 = tt;
        }
        const double cw = twv.x, sw = twv.y;
        #define GFIN(S1, S2, ROW) { \
            double yr = (S1) - cw * (S2); \
            double yi = sw * (S2); \
            double Xr = cw * yr - sw * yi; \
            double Xi = cw * yi + sw * yr; \
            mags[ROW][lane] = Xr * Xr + Xi * Xi; \
            reF[ROW][lane] = (float)Xr; imF[ROW][lane] = (float)Xi; }
        GFIN(s1_0, s2_0, s0 + 0)
        GFIN(s1_1, s2_1, s0 + 1)
        GFIN(s1_2, s2_2, s0 + 2)
        GFIN(s1_3, s2_3, s0 + 3)
        GFIN(s1_4, s2_4, s0 + 4)
        GFIN(s1_5, s2_5, s0 + 5)
        GFIN(s1_6, s2_6, s0 + 6)
        GFIN(s1_7, s2_7, s0 + 7)
        #undef GFIN
    }
    __syncthreads();

    // ---- Phase 3: top-3 per series (fp64, strict > keeps lowest index on ties)
    if (t < NCH) {
        double m1 = -1.0, m2 = -1.0, m3 = -1.0;
        int i1 = 0, i2 = 0, i3 = 0;
        for (int fi = 0; fi < 47; ++fi) {
            double mg = mags[t][fi];
            if (mg > m1)      { m3 = m2; i3 = i2; m2 = m1; i2 = i1; m1 = mg; i1 = fi; }
            else if (mg > m2) { m3 = m2; i3 = i2; m2 = mg; i2 = fi; }
            else if (mg > m3) { m3 = mg; i3 = fi; }
        }
        const float sc = Wsm[t] * (2.0f / 96.0f);
        Fs[t * 3 + 0] = i1 + 1; As[t * 3 + 0] = sc * reF[t][i1]; Bs[t * 3 + 0] = sc * imF[t][i1];
        Fs[t * 3 + 1] = i2 + 1; As[t * 3 + 1] = sc * reF[t][i2]; Bs[t * 3 + 1] = sc * imF[t][i2];
        Fs[t * 3 + 2] = i3 + 1; As[t * 3 + 2] = sc * reF[t][i3]; Bs[t * 3 + 2] = sc * imF[t][i3];
    }
    __syncthreads();

    // ---- Phase 4: y[l] = sum_n xs[n][l] * Ws[n]
    if (t < LENL) {
        float yv = 0.f;
        #pragma unroll
        for (int n = 0; n < NCH; ++n) yv += (float)xd[n][t] * Wsm[n];
        g_sh[t] = yv;
    }
    __syncthreads();

    // ---- Phase 5: g = y + trend(y) + seasonal + b_start (trend is linear in x)
    float gval = 0.f;
    if (t < LENL) {
        float s4 = 0.f;
        #pragma unroll
        for (int j = -1; j <= 2; ++j) {
            int li = t + j; li = li < 0 ? 0 : (li > 95 ? 95 : li);
            s4 += g_sh[li];
        }
        float s8 = s4;
        {
            int li;
            li = t - 3; li = li < 0 ? 0 : li; s8 += g_sh[li];
            li = t - 2; li = li < 0 ? 0 : li; s8 += g_sh[li];
            li = t + 3; li = li > 95 ? 95 : li; s8 += g_sh[li];
            li = t + 4; li = li > 95 ? 95 : li; s8 += g_sh[li];
        }
        float s12 = s8;
        {
            int li;
            li = t - 5; li = li < 0 ? 0 : li; s12 += g_sh[li];
            li = t - 4; li = li < 0 ? 0 : li; s12 += g_sh[li];
            li = t + 5; li = li > 95 ? 95 : li; s12 += g_sh[li];
            li = t + 6; li = li > 95 ? 95 : li; s12 += g_sh[li];
        }
        float tr = (s4 * 0.25f + s8 * 0.125f + s12 * (1.f / 12.f)) * (1.f / 3.f);
        float se = 0.f;
        for (int k = 0; k < 96; ++k) {
            int m = (Fs[k] * t) % LENL;
            float2 c = twf[m];
            se += As[k] * c.x + Bs[k] * c.y;
        }
        gval = g_sh[t] + tr + se + b_start[0];
    }
    __syncthreads();
    if (t < LENL) g_sh[t] = gval;
    __syncthreads();

    // ---- Phase 6: logits, top-2 softmax, combined expert matrix
    if (t < NEXP) {
        float acc = b_gate[t];
        for (int l = 0; l < LENL; ++l) acc += g_sh[l] * W_gate[t * LENL + l];
        logit_s[t] = acc;
    }
    __syncthreads();

    if (t == 0) {
        int i1 = 0;
        for (int e = 1; e < NEXP; ++e) if (logit_s[e] > logit_s[i1]) i1 = e;
        int i2 = (i1 == 0) ? 1 : 0;
        for (int e = 0; e < NEXP; ++e) if (e != i1 && logit_s[e] > logit_s[i2]) i2 = e;
        float v1 = logit_s[i1], v2 = logit_s[i2];
        float e2v = expf(v2 - v1);
        float inv = 1.f / (1.f + e2v);
        esel[0] = i1; esel[1] = i2; gsel[0] = inv; gsel[1] = e2v * inv;
        for (int e = 0; e < NEXP; ++e)
            gws[b * NEXP + e] = (e == i1) ? inv : ((e == i2) ? e2v * inv : 0.f);
    }
    __syncthreads();

    {
        float ga = gsel[0], gb = gsel[1];
        int ea = esel[0], eb = esel[1];
        if (t < CCH * CCH)
            Mws[b * 256 + t] = ga * W_exp[ea * 256 + t] + gb * W_exp[eb * 256 + t];
        if (t >= 240 && t < 240 + CCH) {
            int c = t - 240;
            biasws[b * CCH + c] = ga * b_exp[ea * CCH + c] + gb * b_exp[eb * CCH + c];
        }
    }
}

// ---------------- Kernel 2: out = x + x @ M_b + bias_b (memory-bound) ----------------
__global__ __launch_bounds__(256) void k2_out(
    const float* __restrict__ x,
    const float* __restrict__ Mws,
    const float* __restrict__ biasws,
    float* __restrict__ out)
{
    const int blk = blockIdx.x;
    const int b = blk >> 3;
    const int chunk = blk & 7;
    const int t = threadIdx.x;
    const int lane = t & 63;
    const int wv = t >> 6;
    const int cg = lane & 3;
    const int prow = (wv << 4) + (lane >> 2);

    const float* Mb = Mws + b * 256 + cg * 4;
    float4 m0  = *(const float4*)(Mb + 0 * 16);
    float4 m1  = *(const float4*)(Mb + 1 * 16);
    float4 m2  = *(const float4*)(Mb + 2 * 16);
    float4 m3  = *(const float4*)(Mb + 3 * 16);
    float4 m4  = *(const float4*)(Mb + 4 * 16);
    float4 m5  = *(const float4*)(Mb + 5 * 16);
    float4 m6  = *(const float4*)(Mb + 6 * 16);
    float4 m7  = *(const float4*)(Mb + 7 * 16);
    float4 m8  = *(const float4*)(Mb + 8 * 16);
    float4 m9  = *(const float4*)(Mb + 9 * 16);
    float4 m10 = *(const float4*)(Mb + 10 * 16);
    float4 m11 = *(const float4*)(Mb + 11 * 16);
    float4 m12 = *(const float4*)(Mb + 12 * 16);
    float4 m13 = *(const float4*)(Mb + 13 * 16);
    float4 m14 = *(const float4*)(Mb + 14 * 16);
    float4 m15 = *(const float4*)(Mb + 15 * 16);
    float4 bias = *(const float4*)(biasws + b * CCH + cg * 4);

    const size_t base = (size_t)b * (LENL * NCH * CCH);
    const float* xb = x + base;
    float* ob = out + base;
    const int posBase = chunk * (LENL * NCH / SPLIT);

    #pragma unroll
    for (int i = 0; i < (LENL * NCH / SPLIT) / 64; ++i) {
        int pos = posBase + i * 64 + prow;
        const float* xr = xb + (size_t)pos * CCH;
        float4 x0 = *(const float4*)(xr + 0);
        float4 x1 = *(const float4*)(xr + 4);
        float4 x2 = *(const float4*)(xr + 8);
        float4 x3 = *(const float4*)(xr + 12);
        float4 acc = bias;
        #define STEPF(v, M) acc.x += (v) * (M).x; acc.y += (v) * (M).y; acc.z += (v) * (M).z; acc.w += (v) * (M).w;
        STEPF(x0.x, m0)  STEPF(x0.y, m1)  STEPF(x0.z, m2)  STEPF(x0.w, m3)
        STEPF(x1.x, m4)  STEPF(x1.y, m5)  STEPF(x1.z, m6)  STEPF(x1.w, m7)
        STEPF(x2.x, m8)  STEPF(x2.y, m9)  STEPF(x2.z, m10) STEPF(x2.w, m11)
        STEPF(x3.x, m12) STEPF(x3.y, m13) STEPF(x3.z, m14) STEPF(x3.w, m15)
        #undef STEPF
        float4 xo = (cg == 0) ? x0 : ((cg == 1) ? x1 : ((cg == 2) ? x2 : x3));
        acc.x += xo.x; acc.y += xo.y; acc.z += xo.z; acc.w += xo.w;
        *(float4*)(ob + (size_t)pos * CCH + cg * 4) = acc;
    }
}

// ---------------- Kernel 3: balance loss ----------------
__global__ __launch_bounds__(256) void k3_loss(
    const float* __restrict__ gws, float* __restrict__ loss_out)
{
    __shared__ float sh[8][256];
    const int t = threadIdx.x;
    float imp[4] = {0, 0, 0, 0}, ld[4] = {0, 0, 0, 0};
    for (int b = t; b < NB; b += 256) {
        #pragma unroll
        for (int e = 0; e < 4; ++e) {
            float v = gws[b * 4 + e];
            imp[e] += v;
            ld[e] += (v > 0.f) ? 1.f : 0.f;
        }
    }
    #pragma unroll
    for (int e = 0; e < 4; ++e) { sh[e][t] = imp[e]; sh[4 + e][t] = ld[e]; }
    __syncthreads();
    if (t < 8) {
        float s = 0.f;
        for (int i = 0; i < 256; ++i) s += sh[t][i];
        sh[t][0] = s;
    }
    __syncthreads();
    if (t == 0) {
        float a = sh[0][0], b2 = sh[1][0], c = sh[2][0], d = sh[3][0];
        float mean = (a + b2 + c + d) * 0.25f;
        float var = ((a - mean) * (a - mean) + (b2 - mean) * (b2 - mean) +
                     (c - mean) * (c - mean) + (d - mean) * (d - mean)) * (1.f / 3.f);
        float L1 = var / (mean * mean + 1e-10f);
        a = sh[4][0]; b2 = sh[5][0]; c = sh[6][0]; d = sh[7][0];
        mean = (a + b2 + c + d) * 0.25f;
        var = ((a - mean) * (a - mean) + (b2 - mean) * (b2 - mean) +
               (c - mean) * (c - mean) + (d - mean) * (d - mean)) * (1.f / 3.f);
        float L2 = var / (mean * mean + 1e-10f);
        *loss_out = 0.01f * (L1 + L2);
    }
}

extern "C" void kernel_launch(void* const* d_in, const int* in_sizes, int n_in,
                              void* d_out, int out_size, void* d_ws, size_t ws_size,
                              hipStream_t stream)
{
    const float* x       = (const float*)d_in[0];
    const float* W_start = (const float*)d_in[1];
    const float* b_start = (const float*)d_in[2];
    const float* W_gate  = (const float*)d_in[3];
    const float* b_gate  = (const float*)d_in[4];
    const float* W_exp   = (const float*)d_in[5];
    const float* b_exp   = (const float*)d_in[6];
    float* out = (float*)d_out;

    float* ws = (float*)d_ws;
    double2* tw64 = (double2*)ws;            // 96 double2 = 384 floats
    float* Mws    = ws + 384;                // 512*256
    float* biasws = Mws + NB * 256;          // 512*16
    float* gws    = biasws + NB * CCH;       // 512*4

    k0_init<<<1, 128, 0, stream>>>(tw64);
    kA_gate<<<NB, 256, 0, stream>>>(x, tw64, W_start, b_start, W_gate, b_gate,
                                    W_exp, b_exp, Mws, biasws, gws);
    k2_out<<<NB * SPLIT, 256, 0, stream>>>(x, Mws, biasws, out);
    k3_loss<<<1, 256, 0, stream>>>(gws, out + (size_t)out_size - 1);
}